// Round 12
// baseline (35.735 us; speedup 1.0000x reference)
//
#include <hip/hip_runtime.h>
#include <cstdint>
#include <cstddef>

constexpr int CDIM   = 256;   // channels
constexpr int CR     = 64;    // reduced channels
constexpr int NROW   = 4096;  // tokens per batch
constexpr int NBATCH = 8;

// k1: 256 blocks x 1024 threads (16 waves), 128 rows/block, 8 rows/wave
constexpr int K1_GRID = 256;
constexpr int K1_BPB  = K1_GRID / NBATCH;   // 32 blocks per batch
constexpr int K1_RPB  = NROW / K1_BPB;      // 128 rows per block

// k2: 1024 blocks x 256 threads, 32 rows/block, 8 rows/wave = 2 group-iters
constexpr int K2_GRID = 1024;
constexpr int K2_BPB  = K2_GRID / NBATCH;   // 128 blocks per batch
constexpr int K2_RPB  = NROW / K2_BPB;      // 32 rows per block

// ws: S_part [256*256] f32 | S_fin [8*256] f32 | bests [1024] u64 | u_bf16 | cnt[8]
constexpr size_t OFF_SFIN  = (size_t)K1_GRID * CDIM * sizeof(float);
constexpr size_t OFF_BESTS = OFF_SFIN + (size_t)NBATCH * CDIM * sizeof(float);
constexpr size_t OFF_U     = OFF_BESTS + (size_t)K2_GRID * sizeof(unsigned long long);
constexpr size_t OFF_CNT   = OFF_U + (size_t)NBATCH * NROW * CDIM * 2;
constexpr size_t WS_NEED   = OFF_CNT + 64;

#define SCOPE_AGENT __HIP_MEMORY_SCOPE_AGENT

__device__ __forceinline__ unsigned long long pack_key(float best, int n) {
    unsigned key = __float_as_uint(best);
    key = (key & 0x80000000u) ? ~key : (key | 0x80000000u);   // order-preserving
    return ((unsigned long long)key << 32) | (unsigned)n;
}
__device__ __forceinline__ unsigned bf16rn(float f) {        // RNE f32 -> bf16 bits
    const unsigned b = __float_as_uint(f);
    return (b + 0x7FFFu + ((b >> 16) & 1u)) >> 16;
}
__device__ __forceinline__ unsigned pack2(float a, float b) { // [lo=a, hi=b]
    return bf16rn(a) | (bf16rn(b) << 16);
}
__device__ __forceinline__ float bflo(unsigned u) { return __uint_as_float(u << 16); }
__device__ __forceinline__ float bfhi(unsigned u) { return __uint_as_float(u & 0xFFFF0000u); }

// ---- k1: partial S per block (32/batch) + u rows stored as bf16; zero cnt ----
__global__ __launch_bounds__(1024) void k1(const float* __restrict__ x,
                                           float* __restrict__ S_part,
                                           unsigned* __restrict__ ubuf,  // bf16 pairs
                                           unsigned* __restrict__ cnt,
                                           int store_u) {
    const int blk = blockIdx.x, t = threadIdx.x;
    const int wave = t >> 6, lane = t & 63;
    const int g = lane >> 4, sub = lane & 15;
    __shared__ float comb[16][CDIM];            // 16 KB
    if (blk == 0 && t < NBATCH) cnt[t] = 0u;    // visible to K2 via kernel boundary

    const int b = blk / K1_BPB, chunk = blk % K1_BPB;
    const float* xb = x + (size_t)b * NROW * CDIM;
    const int nbase = chunk * K1_RPB + wave * 8;   // 8 rows per wave

    float4 a0 = {0,0,0,0}, a1 = {0,0,0,0}, a2 = {0,0,0,0}, a3 = {0,0,0,0};
#pragma unroll
    for (int rg = 0; rg < 2; ++rg) {
        const int n = nbase + rg * 4 + g;
        const float* rowp = xb + (size_t)n * CDIM + sub * 4;
        const float4 v0 = *reinterpret_cast<const float4*>(rowp);
        const float4 v1 = *reinterpret_cast<const float4*>(rowp + 64);
        const float4 v2 = *reinterpret_cast<const float4*>(rowp + 128);
        const float4 v3 = *reinterpret_cast<const float4*>(rowp + 192);

        float sa = (v0.x+v0.y+v0.z+v0.w) + (v1.x+v1.y+v1.z+v1.w)
                 + (v2.x+v2.y+v2.z+v2.w) + (v3.x+v3.y+v3.z+v3.w);
        float sb = (v0.x*v0.x+v0.y*v0.y+v0.z*v0.z+v0.w*v0.w)
                 + (v1.x*v1.x+v1.y*v1.y+v1.z*v1.z+v1.w*v1.w)
                 + (v2.x*v2.x+v2.y*v2.y+v2.z*v2.z+v2.w*v2.w)
                 + (v3.x*v3.x+v3.y*v3.y+v3.z*v3.z+v3.w*v3.w);
#pragma unroll
        for (int off = 1; off < 16; off <<= 1) {   // 16-lane group reduce, 4 rows at once
            sa += __shfl_xor(sa, off, 64);
            sb += __shfl_xor(sb, off, 64);
        }
        const float mu  = sa * (1.0f / CDIM);
        const float inv = rsqrtf(sb - sa * mu);    // ln-eps & rsqrt scale cancel in u
        const float u00 = (v0.x-mu)*inv, u01 = (v0.y-mu)*inv, u02 = (v0.z-mu)*inv, u03 = (v0.w-mu)*inv;
        const float u10 = (v1.x-mu)*inv, u11 = (v1.y-mu)*inv, u12 = (v1.z-mu)*inv, u13 = (v1.w-mu)*inv;
        const float u20 = (v2.x-mu)*inv, u21 = (v2.y-mu)*inv, u22 = (v2.z-mu)*inv, u23 = (v2.w-mu)*inv;
        const float u30 = (v3.x-mu)*inv, u31 = (v3.y-mu)*inv, u32 = (v3.z-mu)*inv, u33 = (v3.w-mu)*inv;

        if (store_u) {
            unsigned* up = ubuf + (size_t)((size_t)b * NROW + n) * (CDIM / 2) + sub * 2;
            *reinterpret_cast<uint2*>(up +  0) = make_uint2(pack2(u00,u01), pack2(u02,u03));
            *reinterpret_cast<uint2*>(up + 32) = make_uint2(pack2(u10,u11), pack2(u12,u13));
            *reinterpret_cast<uint2*>(up + 64) = make_uint2(pack2(u20,u21), pack2(u22,u23));
            *reinterpret_cast<uint2*>(up + 96) = make_uint2(pack2(u30,u31), pack2(u32,u33));
        }
        a0.x += u00; a0.y += u01; a0.z += u02; a0.w += u03;
        a1.x += u10; a1.y += u11; a1.z += u12; a1.w += u13;
        a2.x += u20; a2.y += u21; a2.z += u22; a2.w += u23;
        a3.x += u30; a3.y += u31; a3.z += u32; a3.w += u33;
    }
#pragma unroll
    for (int off = 16; off < 64; off <<= 1) {   // fold the 4 row-groups
        a0.x += __shfl_xor(a0.x, off, 64); a0.y += __shfl_xor(a0.y, off, 64);
        a0.z += __shfl_xor(a0.z, off, 64); a0.w += __shfl_xor(a0.w, off, 64);
        a1.x += __shfl_xor(a1.x, off, 64); a1.y += __shfl_xor(a1.y, off, 64);
        a1.z += __shfl_xor(a1.z, off, 64); a1.w += __shfl_xor(a1.w, off, 64);
        a2.x += __shfl_xor(a2.x, off, 64); a2.y += __shfl_xor(a2.y, off, 64);
        a2.z += __shfl_xor(a2.z, off, 64); a2.w += __shfl_xor(a2.w, off, 64);
        a3.x += __shfl_xor(a3.x, off, 64); a3.y += __shfl_xor(a3.y, off, 64);
        a3.z += __shfl_xor(a3.z, off, 64); a3.w += __shfl_xor(a3.w, off, 64);
    }
    if (g == 0) {
        *reinterpret_cast<float4*>(&comb[wave][sub * 4 +   0]) = a0;
        *reinterpret_cast<float4*>(&comb[wave][sub * 4 +  64]) = a1;
        *reinterpret_cast<float4*>(&comb[wave][sub * 4 + 128]) = a2;
        *reinterpret_cast<float4*>(&comb[wave][sub * 4 + 192]) = a3;
    }
    __syncthreads();
    if (t < CDIM) {
        float s = 0.f;
#pragma unroll
        for (int w = 0; w < 16; ++w) s += comb[w][t];
        S_part[(size_t)blk * CDIM + t] = s;
    }
}

// ---- k2f: reduce 32 partials; density from bf16 u; last-block finalize ----
__global__ __launch_bounds__(256) void k2f(const unsigned* __restrict__ ubuf,
                                           const float* __restrict__ S_part,
                                           const float* __restrict__ x,
                                           const float* __restrict__ lnw,
                                           const float* __restrict__ lnb,
                                           const float* __restrict__ pw,
                                           const float* __restrict__ pb,
                                           unsigned long long* bests,
                                           unsigned* cnt,
                                           float* __restrict__ out) {
    const int blk = blockIdx.x, t = threadIdx.x;
    const int wave = t >> 6, lane = t & 63;
    const int g = lane >> 4, sub = lane & 15;
    const int b = blk / K2_BPB, chunk = blk % K2_BPB;

    __shared__ float comb[CDIM];
    __shared__ unsigned long long wbest[4];
    __shared__ int lastflag;
    __shared__ float sred[8];

    {   // S[b] = sum of this batch's 32 partials (plain loads, L2-hot)
        const float* Sp = S_part + (size_t)b * K1_BPB * CDIM;
        float s0 = 0.f, s1 = 0.f, s2 = 0.f, s3 = 0.f;
#pragma unroll
        for (int p = 0; p < K1_BPB; p += 4) {
            s0 += Sp[(size_t)(p + 0) * CDIM + t];
            s1 += Sp[(size_t)(p + 1) * CDIM + t];
            s2 += Sp[(size_t)(p + 2) * CDIM + t];
            s3 += Sp[(size_t)(p + 3) * CDIM + t];
        }
        comb[t] = (s0 + s1) + (s2 + s3);
    }
    __syncthreads();
    const float4* c4p = reinterpret_cast<const float4*>(comb);
    const float4 S0 = c4p[sub * 4 + 0];   // cols 16sub+ 0.. 3
    const float4 S1 = c4p[sub * 4 + 1];
    const float4 S2 = c4p[sub * 4 + 2];
    const float4 S3 = c4p[sub * 4 + 3];

    const unsigned* ub = ubuf + (size_t)b * NROW * (CDIM / 2);
    const int nbase = chunk * K2_RPB + wave * 8;
    float best = -1e30f;
    int   bestn = 0;
#pragma unroll
    for (int rg = 0; rg < 2; ++rg) {
        const int n = nbase + rg * 4 + g;
        const unsigned* rowp = ub + (size_t)n * (CDIM / 2) + sub * 8;
        const uint4 q0 = *reinterpret_cast<const uint4*>(rowp);
        const uint4 q1 = *reinterpret_cast<const uint4*>(rowp + 4);

        float sc = bflo(q0.x)*S0.x + bfhi(q0.x)*S0.y
                 + bflo(q0.y)*S0.z + bfhi(q0.y)*S0.w
                 + bflo(q0.z)*S1.x + bfhi(q0.z)*S1.y
                 + bflo(q0.w)*S1.z + bfhi(q0.w)*S1.w
                 + bflo(q1.x)*S2.x + bfhi(q1.x)*S2.y
                 + bflo(q1.y)*S2.z + bfhi(q1.y)*S2.w
                 + bflo(q1.z)*S3.x + bfhi(q1.z)*S3.y
                 + bflo(q1.w)*S3.z + bfhi(q1.w)*S3.w;
#pragma unroll
        for (int off = 1; off < 16; off <<= 1) sc += __shfl_xor(sc, off, 64);
        if (sc > best) { best = sc; bestn = n; }
    }
    unsigned long long key = pack_key(best, bestn);
    {
        unsigned long long o = __shfl_xor(key, 16, 64); key = o > key ? o : key;
        o = __shfl_xor(key, 32, 64);                    key = o > key ? o : key;
    }
    if (lane == 0) wbest[wave] = key;
    __syncthreads();
    if (t == 0) {
        unsigned long long m = wbest[0];
#pragma unroll
        for (int w = 1; w < 4; ++w) m = m > wbest[w] ? m : wbest[w];
        // returning exchange -> coherence point; data-sink forces vmcnt(0)
        unsigned long long old = __hip_atomic_exchange(&bests[blk], m,
                                     __ATOMIC_RELAXED, SCOPE_AGENT);
        asm volatile("" :: "v"(old));   // visibility before counter bump
        const unsigned prev = __hip_atomic_fetch_add(&cnt[b], 1u,
                                  __ATOMIC_RELAXED, SCOPE_AGENT);
        lastflag = (prev == (unsigned)(K2_BPB - 1));
    }
    __syncthreads();
    if (!lastflag) return;

    // ---- last block of batch b: argmax over 128 bests; LN; proj; relu ----
    unsigned long long v64 = 0ULL;
    if (t < K2_BPB)
        v64 = __hip_atomic_load(&bests[(size_t)b * K2_BPB + t],
                                __ATOMIC_RELAXED, SCOPE_AGENT);
#pragma unroll
    for (int off = 1; off < 64; off <<= 1) {
        const unsigned long long o = __shfl_xor(v64, off, 64);
        v64 = o > v64 ? o : v64;
    }
    if (lane == 0) wbest[wave] = v64;
    __syncthreads();
    unsigned long long m = wbest[0];
#pragma unroll
    for (int w = 1; w < 4; ++w) m = m > wbest[w] ? m : wbest[w];
    const int n = (int)(m & 0xFFFFFFFFULL);

    const float* row = x + ((size_t)b * NROW + n) * CDIM;
    const float v = row[t];

    float s = v;
#pragma unroll
    for (int off = 1; off < 64; off <<= 1) s += __shfl_xor(s, off, 64);
    if (lane == 0) sred[wave] = s;
    __syncthreads();
    const float mu = (sred[0] + sred[1] + sred[2] + sred[3]) * (1.0f / CDIM);

    const float d = v - mu;
    float s2 = d * d;
#pragma unroll
    for (int off = 1; off < 64; off <<= 1) s2 += __shfl_xor(s2, off, 64);
    if (lane == 0) sred[4 + wave] = s2;
    __syncthreads();
    const float var = (sred[4] + sred[5] + sred[6] + sred[7]) * (1.0f / CDIM);
    const float rs  = rsqrtf(var + 1e-5f);

    __syncthreads();                 // comb: S -> y reuse
    comb[t] = d * rs * lnw[t] + lnb[t];
    __syncthreads();

    const int dcol = t >> 2;
    const int part = t & 3;
    const float* wrow = pw + dcol * CDIM + part * 64;
    const float* yp   = &comb[part * 64];
    float p = 0.f;
#pragma unroll
    for (int c = 0; c < 64; ++c) p += yp[c] * wrow[c];
    p += __shfl_xor(p, 1, 64);
    p += __shfl_xor(p, 2, 64);
    if (part == 0) out[b * CR + dcol] = fmaxf(p + pb[dcol], 0.0f);
}

// ==================== fallback chain (ws too small): round-9 style ====================
__global__ __launch_bounds__(256) void ks(const float* __restrict__ S_part,
                                          float* __restrict__ S_fin) {
    const int b = blockIdx.x, t = threadIdx.x;
    const int c4 = t & 63, pg = t >> 6;
    __shared__ float4 acc[4][64];
    const float4* Sp = reinterpret_cast<const float4*>(
        S_part + (size_t)(b * K1_BPB + pg * 8) * CDIM);
    float4 s = {0,0,0,0};
#pragma unroll
    for (int p = 0; p < 8; ++p) {
        const float4 v = Sp[(size_t)p * 64 + c4];
        s.x += v.x; s.y += v.y; s.z += v.z; s.w += v.w;
    }
    acc[pg][c4] = s;
    __syncthreads();
    if (t < 64) {
        const float4 q0 = acc[0][t], q1 = acc[1][t], q2 = acc[2][t], q3 = acc[3][t];
        float4 r;
        r.x = (q0.x + q1.x) + (q2.x + q3.x);
        r.y = (q0.y + q1.y) + (q2.y + q3.y);
        r.z = (q0.z + q1.z) + (q2.z + q3.z);
        r.w = (q0.w + q1.w) + (q2.w + q3.w);
        reinterpret_cast<float4*>(S_fin)[(size_t)b * 64 + t] = r;
    }
}
__global__ __launch_bounds__(256) void k2x(const float* __restrict__ x,
                                           const float* __restrict__ S_fin,
                                           unsigned long long* __restrict__ bests) {
    const int blk = blockIdx.x, t = threadIdx.x;
    const int wave = t >> 6, lane = t & 63;
    const int g = lane >> 4, sub = lane & 15;
    const int b = blk / K2_BPB, chunk = blk % K2_BPB;
    __shared__ float comb[CDIM];
    __shared__ unsigned long long wbest[4];
    comb[t] = S_fin[(size_t)b * CDIM + t];
    __syncthreads();
    const float4* c4p = reinterpret_cast<const float4*>(comb);
    const float4 S0 = c4p[sub * 4 +  0];
    const float4 S1 = c4p[sub * 4 + 16];
    const float4 S2 = c4p[sub * 4 + 32];
    const float4 S3 = c4p[sub * 4 + 48];
    float sumS = (S0.x+S0.y+S0.z+S0.w) + (S1.x+S1.y+S1.z+S1.w)
               + (S2.x+S2.y+S2.z+S2.w) + (S3.x+S3.y+S3.z+S3.w);
#pragma unroll
    for (int off = 1; off < 16; off <<= 1) sumS += __shfl_xor(sumS, off, 64);
    const float* xb = x + (size_t)b * NROW * CDIM;
    const int nbase = chunk * K2_RPB + wave * 8;
    float best = -1e30f; int bestn = 0;
#pragma unroll
    for (int rg = 0; rg < 2; ++rg) {
        const int n = nbase + rg * 4 + g;
        const float* rowp = xb + (size_t)n * CDIM + sub * 4;
        const float4 v0 = *reinterpret_cast<const float4*>(rowp);
        const float4 v1 = *reinterpret_cast<const float4*>(rowp + 64);
        const float4 v2 = *reinterpret_cast<const float4*>(rowp + 128);
        const float4 v3 = *reinterpret_cast<const float4*>(rowp + 192);
        float sa = (v0.x+v0.y+v0.z+v0.w) + (v1.x+v1.y+v1.z+v1.w)
                 + (v2.x+v2.y+v2.z+v2.w) + (v3.x+v3.y+v3.z+v3.w);
        float sb = (v0.x*v0.x+v0.y*v0.y+v0.z*v0.z+v0.w*v0.w)
                 + (v1.x*v1.x+v1.y*v1.y+v1.z*v1.z+v1.w*v1.w)
                 + (v2.x*v2.x+v2.y*v2.y+v2.z*v2.z+v2.w*v2.w)
                 + (v3.x*v3.x+v3.y*v3.y+v3.z*v3.z+v3.w*v3.w);
        float sc = (v0.x*S0.x+v0.y*S0.y+v0.z*S0.z+v0.w*S0.w)
                 + (v1.x*S1.x+v1.y*S1.y+v1.z*S1.z+v1.w*S1.w)
                 + (v2.x*S2.x+v2.y*S2.y+v2.z*S2.z+v2.w*S2.w)
                 + (v3.x*S3.x+v3.y*S3.y+v3.z*S3.z+v3.w*S3.w);
#pragma unroll
        for (int off = 1; off < 16; off <<= 1) {
            sa += __shfl_xor(sa, off, 64);
            sb += __shfl_xor(sb, off, 64);
            sc += __shfl_xor(sc, off, 64);
        }
        const float mu   = sa * (1.0f / CDIM);
        const float dens = (sc - mu * sumS) * rsqrtf(sb - sa * mu);
        if (dens > best) { best = dens; bestn = n; }
    }
    unsigned long long key = pack_key(best, bestn);
    {
        unsigned long long o = __shfl_xor(key, 16, 64); key = o > key ? o : key;
        o = __shfl_xor(key, 32, 64);                    key = o > key ? o : key;
    }
    if (lane == 0) wbest[wave] = key;
    __syncthreads();
    if (t == 0) {
        unsigned long long m = wbest[0];
#pragma unroll
        for (int w = 1; w < 4; ++w) m = m > wbest[w] ? m : wbest[w];
        bests[blk] = m;
    }
}
__global__ __launch_bounds__(256) void k4(const float* __restrict__ x,
                                          const float* __restrict__ lnw,
                                          const float* __restrict__ lnb,
                                          const float* __restrict__ pw,
                                          const float* __restrict__ pb,
                                          const unsigned long long* __restrict__ bests,
                                          float* __restrict__ out) {
    const int bb = blockIdx.x, t = threadIdx.x, wave = t >> 6, lane = t & 63;
    __shared__ unsigned long long wbest[4];
    __shared__ float sred[8];
    __shared__ float y[CDIM];
    unsigned long long v64 = (t < K2_BPB) ? bests[(size_t)bb * K2_BPB + t] : 0ULL;
#pragma unroll
    for (int off = 1; off < 64; off <<= 1) {
        const unsigned long long o = __shfl_xor(v64, off, 64);
        v64 = o > v64 ? o : v64;
    }
    if (lane == 0) wbest[wave] = v64;
    __syncthreads();
    unsigned long long m = wbest[0];
#pragma unroll
    for (int w = 1; w < 4; ++w) m = m > wbest[w] ? m : wbest[w];
    const int n = (int)(m & 0xFFFFFFFFULL);
    const float* row = x + ((size_t)bb * NROW + n) * CDIM;
    const float v = row[t];
    float s = v;
#pragma unroll
    for (int off = 1; off < 64; off <<= 1) s += __shfl_xor(s, off, 64);
    if (lane == 0) sred[wave] = s;
    __syncthreads();
    const float mu = (sred[0] + sred[1] + sred[2] + sred[3]) * (1.0f / CDIM);
    const float d = v - mu;
    float s2 = d * d;
#pragma unroll
    for (int off = 1; off < 64; off <<= 1) s2 += __shfl_xor(s2, off, 64);
    if (lane == 0) sred[4 + wave] = s2;
    __syncthreads();
    const float var = (sred[4] + sred[5] + sred[6] + sred[7]) * (1.0f / CDIM);
    const float rs = rsqrtf(var + 1e-5f);
    y[t] = d * rs * lnw[t] + lnb[t];
    __syncthreads();
    const int dcol = t >> 2, part = t & 3;
    const float* wrow = pw + dcol * CDIM + part * 64;
    const float* yp = y + part * 64;
    float p = 0.f;
#pragma unroll
    for (int c = 0; c < 64; ++c) p += yp[c] * wrow[c];
    p += __shfl_xor(p, 1, 64);
    p += __shfl_xor(p, 2, 64);
    if (part == 0) out[bb * CR + dcol] = fmaxf(p + pb[dcol], 0.0f);
}

// ------------------------------------------------------------------ launch ----
extern "C" void kernel_launch(void* const* d_in, const int* in_sizes, int n_in,
                              void* d_out, int out_size, void* d_ws, size_t ws_size,
                              hipStream_t stream) {
    const float* x   = (const float*)d_in[0];
    const float* lnw = (const float*)d_in[1];
    const float* lnb = (const float*)d_in[2];
    const float* pw  = (const float*)d_in[3];
    const float* pb  = (const float*)d_in[4];
    float* out = (float*)d_out;

    float* S_part = (float*)d_ws;
    float* S_fin  = (float*)((char*)d_ws + OFF_SFIN);
    unsigned long long* bests = (unsigned long long*)((char*)d_ws + OFF_BESTS);
    unsigned* ubuf = (unsigned*)((char*)d_ws + OFF_U);
    unsigned* cnt  = (unsigned*)((char*)d_ws + OFF_CNT);

    if (ws_size >= WS_NEED) {
        k1<<<K1_GRID, 1024, 0, stream>>>(x, S_part, ubuf, cnt, 1);
        k2f<<<K2_GRID, 256, 0, stream>>>(ubuf, S_part, x, lnw, lnb, pw, pb,
                                         bests, cnt, out);
    } else {   // fallback: proven 4-kernel chain
        k1<<<K1_GRID, 1024, 0, stream>>>(x, S_part, ubuf, cnt, 0);
        ks<<<NBATCH,  256,  0, stream>>>(S_part, S_fin);
        k2x<<<K2_GRID, 256, 0, stream>>>(x, S_fin, bests);
        k4<<<NBATCH,  256,  0, stream>>>(x, lnw, lnb, pw, pb, bests, out);
    }
}

// Round 13
// 26.017 us; speedup vs baseline: 1.3735x; 1.3735x over previous
//
#include <hip/hip_runtime.h>
#include <cstdint>
#include <cstddef>

constexpr int CDIM   = 256;   // channels
constexpr int CR     = 64;    // reduced channels
constexpr int NROW   = 4096;  // tokens per batch
constexpr int NBATCH = 8;

// k1: 256 blocks x 1024 threads (16 waves), 128 rows/block, 8 rows/wave
constexpr int K1_GRID = 256;
constexpr int K1_BPB  = K1_GRID / NBATCH;   // 32 blocks per batch
constexpr int K1_RPB  = NROW / K1_BPB;      // 128 rows per block

// k2: 1024 blocks x 256 threads, 32 rows/block, 8 rows/wave = 2 group-iters
constexpr int K2_GRID = 1024;
constexpr int K2_BPB  = K2_GRID / NBATCH;   // 128 blocks per batch
constexpr int K2_RPB  = NROW / K2_BPB;      // 32 rows per block

// ws: S_part [256*256] f32 | bests [1024] u64 | u_bf16 [8*4096*128 u32]
constexpr size_t OFF_BESTS = (size_t)K1_GRID * CDIM * sizeof(float);
constexpr size_t OFF_U     = OFF_BESTS + (size_t)K2_GRID * sizeof(unsigned long long);
constexpr size_t WS_NEED   = OFF_U + (size_t)NBATCH * NROW * CDIM * 2;

__device__ __forceinline__ unsigned long long pack_key(float best, int n) {
    unsigned key = __float_as_uint(best);
    key = (key & 0x80000000u) ? ~key : (key | 0x80000000u);   // order-preserving
    return ((unsigned long long)key << 32) | (unsigned)n;
}
__device__ __forceinline__ unsigned bf16rn(float f) {        // RNE f32 -> bf16 bits
    const unsigned b = __float_as_uint(f);
    return (b + 0x7FFFu + ((b >> 16) & 1u)) >> 16;
}
__device__ __forceinline__ unsigned pack2(float a, float b) { // [lo=a, hi=b]
    return bf16rn(a) | (bf16rn(b) << 16);
}
__device__ __forceinline__ float bflo(unsigned u) { return __uint_as_float(u << 16); }
__device__ __forceinline__ float bfhi(unsigned u) { return __uint_as_float(u & 0xFFFF0000u); }

// ---- k1: partial S per block (32/batch) + u rows stored as bf16 ----
__global__ __launch_bounds__(1024) void k1(const float* __restrict__ x,
                                           float* __restrict__ S_part,
                                           unsigned* __restrict__ ubuf,  // bf16 pairs
                                           int store_u) {
    const int blk = blockIdx.x, t = threadIdx.x;
    const int wave = t >> 6, lane = t & 63;
    const int g = lane >> 4, sub = lane & 15;
    __shared__ float comb[16][CDIM];            // 16 KB

    const int b = blk / K1_BPB, chunk = blk % K1_BPB;
    const float* xb = x + (size_t)b * NROW * CDIM;
    const int nbase = chunk * K1_RPB + wave * 8;   // 8 rows per wave

    float4 a0 = {0,0,0,0}, a1 = {0,0,0,0}, a2 = {0,0,0,0}, a3 = {0,0,0,0};
#pragma unroll
    for (int rg = 0; rg < 2; ++rg) {
        const int n = nbase + rg * 4 + g;
        const float* rowp = xb + (size_t)n * CDIM + sub * 4;
        const float4 v0 = *reinterpret_cast<const float4*>(rowp);
        const float4 v1 = *reinterpret_cast<const float4*>(rowp + 64);
        const float4 v2 = *reinterpret_cast<const float4*>(rowp + 128);
        const float4 v3 = *reinterpret_cast<const float4*>(rowp + 192);

        float sa = (v0.x+v0.y+v0.z+v0.w) + (v1.x+v1.y+v1.z+v1.w)
                 + (v2.x+v2.y+v2.z+v2.w) + (v3.x+v3.y+v3.z+v3.w);
        float sb = (v0.x*v0.x+v0.y*v0.y+v0.z*v0.z+v0.w*v0.w)
                 + (v1.x*v1.x+v1.y*v1.y+v1.z*v1.z+v1.w*v1.w)
                 + (v2.x*v2.x+v2.y*v2.y+v2.z*v2.z+v2.w*v2.w)
                 + (v3.x*v3.x+v3.y*v3.y+v3.z*v3.z+v3.w*v3.w);
#pragma unroll
        for (int off = 1; off < 16; off <<= 1) {   // 16-lane group reduce, 4 rows at once
            sa += __shfl_xor(sa, off, 64);
            sb += __shfl_xor(sb, off, 64);
        }
        const float mu  = sa * (1.0f / CDIM);
        const float inv = rsqrtf(sb - sa * mu);    // ln-eps & rsqrt scale cancel in u
        const float u00 = (v0.x-mu)*inv, u01 = (v0.y-mu)*inv, u02 = (v0.z-mu)*inv, u03 = (v0.w-mu)*inv;
        const float u10 = (v1.x-mu)*inv, u11 = (v1.y-mu)*inv, u12 = (v1.z-mu)*inv, u13 = (v1.w-mu)*inv;
        const float u20 = (v2.x-mu)*inv, u21 = (v2.y-mu)*inv, u22 = (v2.z-mu)*inv, u23 = (v2.w-mu)*inv;
        const float u30 = (v3.x-mu)*inv, u31 = (v3.y-mu)*inv, u32 = (v3.z-mu)*inv, u33 = (v3.w-mu)*inv;

        if (store_u) {
            unsigned* up = ubuf + (size_t)((size_t)b * NROW + n) * (CDIM / 2) + sub * 2;
            *reinterpret_cast<uint2*>(up +  0) = make_uint2(pack2(u00,u01), pack2(u02,u03));
            *reinterpret_cast<uint2*>(up + 32) = make_uint2(pack2(u10,u11), pack2(u12,u13));
            *reinterpret_cast<uint2*>(up + 64) = make_uint2(pack2(u20,u21), pack2(u22,u23));
            *reinterpret_cast<uint2*>(up + 96) = make_uint2(pack2(u30,u31), pack2(u32,u33));
        }
        a0.x += u00; a0.y += u01; a0.z += u02; a0.w += u03;
        a1.x += u10; a1.y += u11; a1.z += u12; a1.w += u13;
        a2.x += u20; a2.y += u21; a2.z += u22; a2.w += u23;
        a3.x += u30; a3.y += u31; a3.z += u32; a3.w += u33;
    }
#pragma unroll
    for (int off = 16; off < 64; off <<= 1) {   // fold the 4 row-groups
        a0.x += __shfl_xor(a0.x, off, 64); a0.y += __shfl_xor(a0.y, off, 64);
        a0.z += __shfl_xor(a0.z, off, 64); a0.w += __shfl_xor(a0.w, off, 64);
        a1.x += __shfl_xor(a1.x, off, 64); a1.y += __shfl_xor(a1.y, off, 64);
        a1.z += __shfl_xor(a1.z, off, 64); a1.w += __shfl_xor(a1.w, off, 64);
        a2.x += __shfl_xor(a2.x, off, 64); a2.y += __shfl_xor(a2.y, off, 64);
        a2.z += __shfl_xor(a2.z, off, 64); a2.w += __shfl_xor(a2.w, off, 64);
        a3.x += __shfl_xor(a3.x, off, 64); a3.y += __shfl_xor(a3.y, off, 64);
        a3.z += __shfl_xor(a3.z, off, 64); a3.w += __shfl_xor(a3.w, off, 64);
    }
    if (g == 0) {
        *reinterpret_cast<float4*>(&comb[wave][sub * 4 +   0]) = a0;
        *reinterpret_cast<float4*>(&comb[wave][sub * 4 +  64]) = a1;
        *reinterpret_cast<float4*>(&comb[wave][sub * 4 + 128]) = a2;
        *reinterpret_cast<float4*>(&comb[wave][sub * 4 + 192]) = a3;
    }
    __syncthreads();
    if (t < CDIM) {
        float s = 0.f;
#pragma unroll
        for (int w = 0; w < 16; ++w) s += comb[w][t];
        S_part[(size_t)blk * CDIM + t] = s;
    }
}

// shared prologue: reduce this batch's 32 partials into comb[256] (ks inlined)
__device__ __forceinline__ void reduce_partials(const float* __restrict__ S_part,
                                                int b, int t,
                                                float (&acc4)[4][CDIM],
                                                float (&comb)[CDIM]) {
    const int c = t & 63, pg = t >> 6;          // 4 groups x 8 partials
    const float4* Sp = reinterpret_cast<const float4*>(
        S_part + (size_t)b * K1_BPB * CDIM);
    float4 s = {0, 0, 0, 0};
#pragma unroll
    for (int p = 0; p < 8; ++p) {
        const float4 v = Sp[(size_t)(pg * 8 + p) * 64 + c];
        s.x += v.x; s.y += v.y; s.z += v.z; s.w += v.w;
    }
    *reinterpret_cast<float4*>(&acc4[pg][c * 4]) = s;
    __syncthreads();
    comb[t] = (acc4[0][t] + acc4[1][t]) + (acc4[2][t] + acc4[3][t]);
    __syncthreads();
}

// ---- k2u: inline S reduce; density = u_bf16 . S; per-block best ----
__global__ __launch_bounds__(256) void k2u(const unsigned* __restrict__ ubuf,
                                           const float* __restrict__ S_part,
                                           unsigned long long* __restrict__ bests) {
    const int blk = blockIdx.x, t = threadIdx.x;
    const int wave = t >> 6, lane = t & 63;
    const int g = lane >> 4, sub = lane & 15;
    const int b = blk / K2_BPB, chunk = blk % K2_BPB;

    __shared__ float acc4[4][CDIM];
    __shared__ float comb[CDIM];
    __shared__ unsigned long long wbest[4];

    reduce_partials(S_part, b, t, acc4, comb);

    const float4* c4p = reinterpret_cast<const float4*>(comb);
    const float4 S0 = c4p[sub * 4 + 0];   // cols 16sub+ 0.. 3
    const float4 S1 = c4p[sub * 4 + 1];
    const float4 S2 = c4p[sub * 4 + 2];
    const float4 S3 = c4p[sub * 4 + 3];

    const unsigned* ub = ubuf + (size_t)b * NROW * (CDIM / 2);
    const int nbase = chunk * K2_RPB + wave * 8;
    float best = -1e30f;
    int   bestn = 0;
#pragma unroll
    for (int rg = 0; rg < 2; ++rg) {
        const int n = nbase + rg * 4 + g;
        const unsigned* rowp = ub + (size_t)n * (CDIM / 2) + sub * 8;
        const uint4 q0 = *reinterpret_cast<const uint4*>(rowp);
        const uint4 q1 = *reinterpret_cast<const uint4*>(rowp + 4);

        float sc = bflo(q0.x)*S0.x + bfhi(q0.x)*S0.y
                 + bflo(q0.y)*S0.z + bfhi(q0.y)*S0.w
                 + bflo(q0.z)*S1.x + bfhi(q0.z)*S1.y
                 + bflo(q0.w)*S1.z + bfhi(q0.w)*S1.w
                 + bflo(q1.x)*S2.x + bfhi(q1.x)*S2.y
                 + bflo(q1.y)*S2.z + bfhi(q1.y)*S2.w
                 + bflo(q1.z)*S3.x + bfhi(q1.z)*S3.y
                 + bflo(q1.w)*S3.z + bfhi(q1.w)*S3.w;
#pragma unroll
        for (int off = 1; off < 16; off <<= 1) sc += __shfl_xor(sc, off, 64);
        if (sc > best) { best = sc; bestn = n; }
    }
    unsigned long long key = pack_key(best, bestn);
    {
        unsigned long long o = __shfl_xor(key, 16, 64); key = o > key ? o : key;
        o = __shfl_xor(key, 32, 64);                    key = o > key ? o : key;
    }
    if (lane == 0) wbest[wave] = key;
    __syncthreads();
    if (t == 0) {
        unsigned long long m = wbest[0];
#pragma unroll
        for (int w = 1; w < 4; ++w) m = m > wbest[w] ? m : wbest[w];
        bests[blk] = m;
    }
}

// ---- k2x: fallback (ws too small): density from x re-read ----
__global__ __launch_bounds__(256) void k2x(const float* __restrict__ x,
                                           const float* __restrict__ S_part,
                                           unsigned long long* __restrict__ bests) {
    const int blk = blockIdx.x, t = threadIdx.x;
    const int wave = t >> 6, lane = t & 63;
    const int g = lane >> 4, sub = lane & 15;
    const int b = blk / K2_BPB, chunk = blk % K2_BPB;

    __shared__ float acc4[4][CDIM];
    __shared__ float comb[CDIM];
    __shared__ unsigned long long wbest[4];

    reduce_partials(S_part, b, t, acc4, comb);

    const float4* c4p = reinterpret_cast<const float4*>(comb);
    const float4 S0 = c4p[sub * 4 +  0];   // cols 4sub (seg0)
    const float4 S1 = c4p[sub * 4 + 16];
    const float4 S2 = c4p[sub * 4 + 32];
    const float4 S3 = c4p[sub * 4 + 48];
    float sumS = (S0.x+S0.y+S0.z+S0.w) + (S1.x+S1.y+S1.z+S1.w)
               + (S2.x+S2.y+S2.z+S2.w) + (S3.x+S3.y+S3.z+S3.w);
#pragma unroll
    for (int off = 1; off < 16; off <<= 1) sumS += __shfl_xor(sumS, off, 64);

    const float* xb = x + (size_t)b * NROW * CDIM;
    const int nbase = chunk * K2_RPB + wave * 8;
    float best = -1e30f; int bestn = 0;
#pragma unroll
    for (int rg = 0; rg < 2; ++rg) {
        const int n = nbase + rg * 4 + g;
        const float* rowp = xb + (size_t)n * CDIM + sub * 4;
        const float4 v0 = *reinterpret_cast<const float4*>(rowp);
        const float4 v1 = *reinterpret_cast<const float4*>(rowp + 64);
        const float4 v2 = *reinterpret_cast<const float4*>(rowp + 128);
        const float4 v3 = *reinterpret_cast<const float4*>(rowp + 192);
        float sa = (v0.x+v0.y+v0.z+v0.w) + (v1.x+v1.y+v1.z+v1.w)
                 + (v2.x+v2.y+v2.z+v2.w) + (v3.x+v3.y+v3.z+v3.w);
        float sb = (v0.x*v0.x+v0.y*v0.y+v0.z*v0.z+v0.w*v0.w)
                 + (v1.x*v1.x+v1.y*v1.y+v1.z*v1.z+v1.w*v1.w)
                 + (v2.x*v2.x+v2.y*v2.y+v2.z*v2.z+v2.w*v2.w)
                 + (v3.x*v3.x+v3.y*v3.y+v3.z*v3.z+v3.w*v3.w);
        float sc = (v0.x*S0.x+v0.y*S0.y+v0.z*S0.z+v0.w*S0.w)
                 + (v1.x*S1.x+v1.y*S1.y+v1.z*S1.z+v1.w*S1.w)
                 + (v2.x*S2.x+v2.y*S2.y+v2.z*S2.z+v2.w*S2.w)
                 + (v3.x*S3.x+v3.y*S3.y+v3.z*S3.z+v3.w*S3.w);
#pragma unroll
        for (int off = 1; off < 16; off <<= 1) {
            sa += __shfl_xor(sa, off, 64);
            sb += __shfl_xor(sb, off, 64);
            sc += __shfl_xor(sc, off, 64);
        }
        const float mu   = sa * (1.0f / CDIM);
        const float dens = (sc - mu * sumS) * rsqrtf(sb - sa * mu);
        if (dens > best) { best = dens; bestn = n; }
    }
    unsigned long long key = pack_key(best, bestn);
    {
        unsigned long long o = __shfl_xor(key, 16, 64); key = o > key ? o : key;
        o = __shfl_xor(key, 32, 64);                    key = o > key ? o : key;
    }
    if (lane == 0) wbest[wave] = key;
    __syncthreads();
    if (t == 0) {
        unsigned long long m = wbest[0];
#pragma unroll
        for (int w = 1; w < 4; ++w) m = m > wbest[w] ? m : wbest[w];
        bests[blk] = m;
    }
}

// ---- k4: argmax over 128 bests; LN(argmax row, full f32) -> proj -> relu ----
__global__ __launch_bounds__(256) void k4(const float* __restrict__ x,
                                          const float* __restrict__ lnw,
                                          const float* __restrict__ lnb,
                                          const float* __restrict__ pw,
                                          const float* __restrict__ pb,
                                          const unsigned long long* __restrict__ bests,
                                          float* __restrict__ out) {
    const int bb = blockIdx.x, t = threadIdx.x, wave = t >> 6, lane = t & 63;
    __shared__ unsigned long long wbest[4];
    __shared__ float sred[8];
    __shared__ float y[CDIM];

    unsigned long long v64 = (t < K2_BPB) ? bests[(size_t)bb * K2_BPB + t] : 0ULL;
#pragma unroll
    for (int off = 1; off < 64; off <<= 1) {
        const unsigned long long o = __shfl_xor(v64, off, 64);
        v64 = o > v64 ? o : v64;
    }
    if (lane == 0) wbest[wave] = v64;
    __syncthreads();
    unsigned long long m = wbest[0];
#pragma unroll
    for (int w = 1; w < 4; ++w) m = m > wbest[w] ? m : wbest[w];
    const int n = (int)(m & 0xFFFFFFFFULL);

    const float* row = x + ((size_t)bb * NROW + n) * CDIM;
    const float v = row[t];

    float s = v;
#pragma unroll
    for (int off = 1; off < 64; off <<= 1) s += __shfl_xor(s, off, 64);
    if (lane == 0) sred[wave] = s;
    __syncthreads();
    const float mu = (sred[0] + sred[1] + sred[2] + sred[3]) * (1.0f / CDIM);

    const float d = v - mu;
    float s2 = d * d;
#pragma unroll
    for (int off = 1; off < 64; off <<= 1) s2 += __shfl_xor(s2, off, 64);
    if (lane == 0) sred[4 + wave] = s2;
    __syncthreads();
    const float var = (sred[4] + sred[5] + sred[6] + sred[7]) * (1.0f / CDIM);
    const float rs  = rsqrtf(var + 1e-5f);

    y[t] = d * rs * lnw[t] + lnb[t];
    __syncthreads();

    const int dcol = t >> 2;
    const int part = t & 3;
    const float* wrow = pw + dcol * CDIM + part * 64;
    const float* yp   = y + part * 64;
    float p = 0.f;
#pragma unroll
    for (int c = 0; c < 64; ++c) p += yp[c] * wrow[c];
    p += __shfl_xor(p, 1, 64);
    p += __shfl_xor(p, 2, 64);
    if (part == 0) out[bb * CR + dcol] = fmaxf(p + pb[dcol], 0.0f);
}

// ------------------------------------------------------------------ launch ----
extern "C" void kernel_launch(void* const* d_in, const int* in_sizes, int n_in,
                              void* d_out, int out_size, void* d_ws, size_t ws_size,
                              hipStream_t stream) {
    const float* x   = (const float*)d_in[0];
    const float* lnw = (const float*)d_in[1];
    const float* lnb = (const float*)d_in[2];
    const float* pw  = (const float*)d_in[3];
    const float* pb  = (const float*)d_in[4];
    float* out = (float*)d_out;

    float* S_part = (float*)d_ws;
    unsigned long long* bests = (unsigned long long*)((char*)d_ws + OFF_BESTS);
    unsigned* ubuf = (unsigned*)((char*)d_ws + OFF_U);

    const int use_u = (ws_size >= WS_NEED) ? 1 : 0;

    k1<<<K1_GRID, 1024, 0, stream>>>(x, S_part, ubuf, use_u);
    if (use_u) k2u<<<K2_GRID, 256, 0, stream>>>(ubuf, S_part, bests);
    else       k2x<<<K2_GRID, 256, 0, stream>>>(x, S_part, bests);
    k4<<<NBATCH, 256, 0, stream>>>(x, lnw, lnb, pw, pb, bests, out);
}